// Round 2
// baseline (1424.206 us; speedup 1.0000x reference)
//
#include <hip/hip_runtime.h>
#include <hip/hip_bf16.h>

#define H 128
#define NGRAPH 512
#define NPB 32   // nodes per block in node_transform

// ---------------- scatter-add of edge attrs onto nodes ----------------
// thread = (edge, quad q in 0..31); handles features q, q+32, q+64, q+96.
// Loads and atomics are lane-consecutive (128B segments per 32 lanes).
__global__ __launch_bounds__(256) void scatter_edges(
    const float* __restrict__ attr1, const float* __restrict__ attr2,
    const int* __restrict__ idx1, const int* __restrict__ idx2,
    float* __restrict__ node_acc, int E)
{
    long long gid = (long long)blockIdx.x * 256 + threadIdx.x;
    long long EE = (long long)E * 32;
    if (gid >= 2 * EE) return;
    const float* attr; const int* idx; long long r;
    if (gid < EE) { attr = attr1; idx = idx1; r = gid; }
    else          { attr = attr2; idx = idx2; r = gid - EE; }
    int e = (int)(r >> 5);
    int q = (int)(r & 31);
    int node = idx[e];
    const float* src = attr + (long long)e * H + q;
    float* dst = node_acc + (long long)node * H + q;
    unsafeAtomicAdd(dst +  0, src[ 0]);
    unsafeAtomicAdd(dst + 32, src[32]);
    unsafeAtomicAdd(dst + 64, src[64]);
    unsafeAtomicAdd(dst + 96, src[96]);
}

// ---------------- transpose W into workspace: WtG[k*H + j] = W[j*H + k] ----
__global__ __launch_bounds__(256) void transpose_W(
    const float* __restrict__ W, float* __restrict__ WtG)
{
    int i = blockIdx.x * 256 + threadIdx.x;   // 0 .. H*H-1
    int j = i >> 7, k = i & (H - 1);
    WtG[k * H + j] = W[j * H + k];
}

// ---------------- per-node Linear + ELU + pooled atomic add ---------------
__global__ __launch_bounds__(256) void node_transform(
    const float* __restrict__ node_acc, const float* __restrict__ e0,
    const int* __restrict__ batch, const float* __restrict__ WtG,
    const float* __restrict__ bias, float* __restrict__ graph_acc, int N)
{
    __shared__ __align__(16) float xsT[H * 36];  // [k][n], row stride 36 (144B, 16B-aligned)
    __shared__ int bs[NPB];

    int t = threadIdx.x;
    int node0 = blockIdx.x * NPB;

    if (t < NPB) {
        int gn = node0 + t;
        bs[t] = (gn < N) ? batch[gn] : -1;
    }
    // stage x = node_acc + edge_attr0, transposed
    for (int i = t; i < NPB * H; i += 256) {
        int n = i >> 7, k = i & (H - 1);
        int gn = node0 + n;
        float v = 0.f;
        if (gn < N) {
            long long o = (long long)gn * H + k;
            v = node_acc[o] + e0[o];
        }
        xsT[k * 36 + n] = v;
    }
    __syncthreads();

    int n0 = (t & 7) * 4;
    int j0 = (t >> 3) * 4;

    float acc[4][4] = {};
    #pragma unroll 4
    for (int k = 0; k < H; ++k) {
        float xr[4], wr[4];
        *(float4*)xr = *(const float4*)&xsT[k * 36 + n0];
        *(float4*)wr = *(const float4*)&WtG[k * H + j0];
        #pragma unroll
        for (int nn = 0; nn < 4; ++nn)
            #pragma unroll
            for (int jj = 0; jj < 4; ++jj)
                acc[nn][jj] = fmaf(xr[nn], wr[jj], acc[nn][jj]);
    }

    float bj[4];
    *(float4*)bj = *(const float4*)&bias[j0];

    // ELU then graph accumulation; run-length compress over this thread's
    // 4 (sorted) nodes to cut same-address atomic contention.
    #pragma unroll
    for (int jj = 0; jj < 4; ++jj) {
        int j = j0 + jj;
        int curg = -1; float s = 0.f;
        #pragma unroll
        for (int nn = 0; nn < 4; ++nn) {
            int g = bs[n0 + nn];
            if (g < 0) continue;
            float a = acc[nn][jj] + bj[jj];
            float y = (a > 0.f) ? a : expm1f(a);
            if (g == curg) { s += y; }
            else {
                if (curg >= 0) unsafeAtomicAdd(&graph_acc[curg * H + j], s);
                curg = g; s = y;
            }
        }
        if (curg >= 0) unsafeAtomicAdd(&graph_acc[curg * H + j], s);
    }
}

// ---------------- divide by per-graph counts (binary search, no atomics) ---
__device__ __forceinline__ int lower_bound_dev(const int* __restrict__ b, int n, int v) {
    int lo = 0, hi = n;
    while (lo < hi) { int m = (lo + hi) >> 1; if (b[m] < v) lo = m + 1; else hi = m; }
    return lo;
}

__global__ __launch_bounds__(256) void finalize(
    const float* __restrict__ graph_acc, const int* __restrict__ batch,
    float* __restrict__ out, int N)
{
    int i = blockIdx.x * 256 + threadIdx.x;
    if (i >= NGRAPH * H) return;
    int g = i >> 7;
    int lo = lower_bound_dev(batch, N, g);
    int hi = lower_bound_dev(batch, N, g + 1);
    float c = fmaxf((float)(hi - lo), 1.0f);
    out[i] = graph_acc[i] / c;
}

extern "C" void kernel_launch(void* const* d_in, const int* in_sizes, int n_in,
                              void* d_out, int out_size, void* d_ws, size_t ws_size,
                              hipStream_t stream)
{
    const float* e0    = (const float*)d_in[0];
    const float* a1    = (const float*)d_in[1];
    const float* a2    = (const float*)d_in[2];
    const int*   i1    = (const int*)d_in[3];
    const int*   i2    = (const int*)d_in[4];
    const int*   batch = (const int*)d_in[5];
    const float* W     = (const float*)d_in[7];
    const float* b     = (const float*)d_in[8];
    float* out = (float*)d_out;

    int N = in_sizes[0] / H;
    int E = in_sizes[3];

    char* ws = (char*)d_ws;
    size_t node_bytes = (size_t)N * H * sizeof(float);
    size_t ga_bytes   = (size_t)NGRAPH * H * sizeof(float);
    float* node_acc  = (float*)ws;
    float* graph_acc = (float*)(ws + node_bytes);
    float* WtG       = (float*)(ws + node_bytes + ga_bytes);

    hipMemsetAsync(node_acc, 0, node_bytes + ga_bytes, stream);
    transpose_W<<<(H * H + 255) / 256, 256, 0, stream>>>(W, WtG);

    long long totB = 2LL * E * 32;
    int nbB = (int)((totB + 255) / 256);
    scatter_edges<<<nbB, 256, 0, stream>>>(a1, a2, i1, i2, node_acc, E);

    node_transform<<<(N + NPB - 1) / NPB, 256, 0, stream>>>(
        node_acc, e0, batch, WtG, b, graph_acc, N);

    finalize<<<(NGRAPH * H + 255) / 256, 256, 0, stream>>>(graph_acc, batch, out, N);
}

// Round 4
// 934.917 us; speedup vs baseline: 1.5233x; 1.5233x over previous
//
#include <hip/hip_runtime.h>
#include <hip/hip_bf16.h>

#define H 128
#define NGRAPH 512
#define NPB 32   // nodes per block in node_transform

// ================= CSR build =================

__global__ __launch_bounds__(256) void hist_kernel(
    const int* __restrict__ i1, const int* __restrict__ i2,
    int* __restrict__ deg, int E)
{
    int t = blockIdx.x * 256 + threadIdx.x;
    if (t >= 2 * E) return;
    int node = (t < E) ? i1[t] : i2[t - E];
    atomicAdd(&deg[node], 1);
}

__global__ __launch_bounds__(256) void scan_partials(
    const int* __restrict__ deg, int* __restrict__ partial, int N)
{
    __shared__ int s[256];
    int t = threadIdx.x;
    int i = blockIdx.x * 256 + t;
    s[t] = (i < N) ? deg[i] : 0;
    __syncthreads();
    for (int off = 128; off > 0; off >>= 1) {
        if (t < off) s[t] += s[t + off];
        __syncthreads();
    }
    if (t == 0) partial[blockIdx.x] = s[0];
}

__global__ void scan_offsets(int* __restrict__ partial, int nb)
{
    if (threadIdx.x == 0 && blockIdx.x == 0) {
        int run = 0;
        for (int i = 0; i < nb; ++i) { int v = partial[i]; partial[i] = run; run += v; }
    }
}

__global__ __launch_bounds__(256) void scan_final(
    const int* __restrict__ deg, const int* __restrict__ partial,
    int* __restrict__ row_ptr, int* __restrict__ pos, int N)
{
    __shared__ int s[256];
    int t = threadIdx.x;
    int i = blockIdx.x * 256 + t;
    int v = (i < N) ? deg[i] : 0;
    s[t] = v;
    __syncthreads();
    for (int off = 1; off < 256; off <<= 1) {
        int tmp = (t >= off) ? s[t - off] : 0;
        __syncthreads();
        s[t] += tmp;
        __syncthreads();
    }
    if (i < N) {
        int excl = partial[blockIdx.x] + s[t] - v;
        row_ptr[i] = excl;
        pos[i] = excl;
    }
}

__global__ __launch_bounds__(256) void fill_kernel(
    const int* __restrict__ i1, const int* __restrict__ i2,
    int* __restrict__ pos, int* __restrict__ adj, int E)
{
    int t = blockIdx.x * 256 + threadIdx.x;
    if (t >= 2 * E) return;
    int node = (t < E) ? i1[t] : i2[t - E];
    int slot = atomicAdd(&pos[node], 1);
    adj[slot] = t;
}

// ================= gather: x[n] = sum(attr rows) + e0[n] =================
// one wave per node; lane owns features {2*lane, 2*lane+1}; each edge row
// read is a contiguous 512B block (64 lanes x float2), 4 rows in flight.
__global__ __launch_bounds__(256) void gather_nodes(
    const float* __restrict__ a1, const float* __restrict__ a2,
    const float* __restrict__ e0, const int* __restrict__ adj,
    const int* __restrict__ row_ptr, const int* __restrict__ deg,
    float* __restrict__ x, int N, int E)
{
    int wave = threadIdx.x >> 6, lane = threadIdx.x & 63;
    int n = blockIdx.x * 4 + wave;
    if (n >= N) return;
    int start = row_ptr[n], d = deg[n];
    float ax = 0.f, ay = 0.f;
    int i = 0;
    for (; i + 4 <= d; i += 4) {
        int t0 = adj[start + i + 0], t1 = adj[start + i + 1];
        int t2 = adj[start + i + 2], t3 = adj[start + i + 3];
        const float* p0 = (t0 < E) ? a1 + (size_t)t0 * H : a2 + (size_t)(t0 - E) * H;
        const float* p1 = (t1 < E) ? a1 + (size_t)t1 * H : a2 + (size_t)(t1 - E) * H;
        const float* p2 = (t2 < E) ? a1 + (size_t)t2 * H : a2 + (size_t)(t2 - E) * H;
        const float* p3 = (t3 < E) ? a1 + (size_t)t3 * H : a2 + (size_t)(t3 - E) * H;
        float2 v0 = *(const float2*)(p0 + lane * 2);
        float2 v1 = *(const float2*)(p1 + lane * 2);
        float2 v2 = *(const float2*)(p2 + lane * 2);
        float2 v3 = *(const float2*)(p3 + lane * 2);
        ax += v0.x + v1.x + v2.x + v3.x;
        ay += v0.y + v1.y + v2.y + v3.y;
    }
    for (; i < d; ++i) {
        int t0 = adj[start + i];
        const float* p0 = (t0 < E) ? a1 + (size_t)t0 * H : a2 + (size_t)(t0 - E) * H;
        float2 v0 = *(const float2*)(p0 + lane * 2);
        ax += v0.x; ay += v0.y;
    }
    size_t o = (size_t)n * H + lane * 2;
    float2 ev = *(const float2*)(e0 + o);
    float2 r; r.x = ax + ev.x; r.y = ay + ev.y;
    *(float2*)(x + o) = r;
}

// ================= fallback scatter (if ws too small) =================
__global__ __launch_bounds__(256) void scatter_edges(
    const float* __restrict__ attr1, const float* __restrict__ attr2,
    const int* __restrict__ idx1, const int* __restrict__ idx2,
    float* __restrict__ node_acc, int E)
{
    long long gid = (long long)blockIdx.x * 256 + threadIdx.x;
    long long EE = (long long)E * 32;
    if (gid >= 2 * EE) return;
    const float* attr; const int* idx; long long r;
    if (gid < EE) { attr = attr1; idx = idx1; r = gid; }
    else          { attr = attr2; idx = idx2; r = gid - EE; }
    int e = (int)(r >> 5);
    int q = (int)(r & 31);
    int node = idx[e];
    const float* src = attr + (long long)e * H + q;
    float* dst = node_acc + (long long)node * H + q;
    unsafeAtomicAdd(dst +  0, src[ 0]);
    unsafeAtomicAdd(dst + 32, src[32]);
    unsafeAtomicAdd(dst + 64, src[64]);
    unsafeAtomicAdd(dst + 96, src[96]);
}

// ================= W transpose =================
__global__ __launch_bounds__(256) void transpose_W(
    const float* __restrict__ W, float* __restrict__ WtG)
{
    int i = blockIdx.x * 256 + threadIdx.x;
    int j = i >> 7, k = i & (H - 1);
    WtG[k * H + j] = W[j * H + k];
}

// ================= per-node Linear + ELU + pooled atomic add =============
// e0_or_null: if non-null, added during staging (fallback path).
__global__ __launch_bounds__(256) void node_transform(
    const float* __restrict__ xin, const float* __restrict__ e0_or_null,
    const int* __restrict__ batch, const float* __restrict__ WtG,
    const float* __restrict__ bias, float* __restrict__ graph_acc, int N)
{
    __shared__ __align__(16) float xsT[H * 36];  // [k][n], row stride 36
    __shared__ int bs[NPB];

    int t = threadIdx.x;
    int node0 = blockIdx.x * NPB;

    if (t < NPB) {
        int gn = node0 + t;
        bs[t] = (gn < N) ? batch[gn] : -1;
    }
    for (int i = t; i < NPB * H; i += 256) {
        int n = i >> 7, k = i & (H - 1);
        int gn = node0 + n;
        float v = 0.f;
        if (gn < N) {
            long long o = (long long)gn * H + k;
            v = xin[o];
            if (e0_or_null) v += e0_or_null[o];
        }
        xsT[k * 36 + n] = v;
    }
    __syncthreads();

    int n0 = (t & 7) * 4;
    int j0 = (t >> 3) * 4;

    float acc[4][4] = {};
    #pragma unroll 4
    for (int k = 0; k < H; ++k) {
        float xr[4], wr[4];
        *(float4*)xr = *(const float4*)&xsT[k * 36 + n0];
        *(float4*)wr = *(const float4*)&WtG[k * H + j0];
        #pragma unroll
        for (int nn = 0; nn < 4; ++nn)
            #pragma unroll
            for (int jj = 0; jj < 4; ++jj)
                acc[nn][jj] = fmaf(xr[nn], wr[jj], acc[nn][jj]);
    }

    float bj[4];
    *(float4*)bj = *(const float4*)&bias[j0];

    #pragma unroll
    for (int jj = 0; jj < 4; ++jj) {
        int j = j0 + jj;
        int curg = -1; float s = 0.f;
        #pragma unroll
        for (int nn = 0; nn < 4; ++nn) {
            int g = bs[n0 + nn];
            if (g < 0) continue;
            float a = acc[nn][jj] + bj[jj];
            float y = (a > 0.f) ? a : expm1f(a);
            if (g == curg) { s += y; }
            else {
                if (curg >= 0) unsafeAtomicAdd(&graph_acc[curg * H + j], s);
                curg = g; s = y;
            }
        }
        if (curg >= 0) unsafeAtomicAdd(&graph_acc[curg * H + j], s);
    }
}

// ================= finalize: divide by per-graph counts =================
__device__ __forceinline__ int lower_bound_dev(const int* __restrict__ b, int n, int v) {
    int lo = 0, hi = n;
    while (lo < hi) { int m = (lo + hi) >> 1; if (b[m] < v) lo = m + 1; else hi = m; }
    return lo;
}

__global__ __launch_bounds__(256) void finalize(
    const float* __restrict__ graph_acc, const int* __restrict__ batch,
    float* __restrict__ out, int N)
{
    int i = blockIdx.x * 256 + threadIdx.x;
    if (i >= NGRAPH * H) return;
    int g = i >> 7;
    int lo = lower_bound_dev(batch, N, g);
    int hi = lower_bound_dev(batch, N, g + 1);
    float c = fmaxf((float)(hi - lo), 1.0f);
    out[i] = graph_acc[i] / c;
}

extern "C" void kernel_launch(void* const* d_in, const int* in_sizes, int n_in,
                              void* d_out, int out_size, void* d_ws, size_t ws_size,
                              hipStream_t stream)
{
    const float* e0    = (const float*)d_in[0];
    const float* a1    = (const float*)d_in[1];
    const float* a2    = (const float*)d_in[2];
    const int*   i1    = (const int*)d_in[3];
    const int*   i2    = (const int*)d_in[4];
    const int*   batch = (const int*)d_in[5];
    const float* W     = (const float*)d_in[7];
    const float* b     = (const float*)d_in[8];
    float* out = (float*)d_out;

    int N = in_sizes[0] / H;
    int E = in_sizes[3];
    int NBS = (N + 255) / 256;              // scan chunks

    auto align16 = [](size_t v) { return (v + 15) & ~(size_t)15; };

    char* ws = (char*)d_ws;
    size_t xB    = align16((size_t)N * H * sizeof(float));
    size_t gaB   = align16((size_t)NGRAPH * H * sizeof(float));
    size_t degB  = align16((size_t)N * sizeof(int));
    size_t rowB  = degB, posB = degB;
    size_t chB   = align16((size_t)NBS * sizeof(int));
    size_t wtB   = align16((size_t)H * H * sizeof(float));
    size_t adjB  = align16((size_t)2 * E * sizeof(int));

    size_t off = 0;
    float* x         = (float*)(ws + off); off += xB;
    float* graph_acc = (float*)(ws + off); off += gaB;
    int*   deg       = (int*)  (ws + off); off += degB;
    int*   row_ptr   = (int*)  (ws + off); off += rowB;
    int*   pos       = (int*)  (ws + off); off += posB;
    int*   chunk     = (int*)  (ws + off); off += chB;
    float* WtG       = (float*)(ws + off); off += wtB;
    int*   adj       = (int*)  (ws + off); off += adjB;

    int nbE = (2 * E + 255) / 256;

    if (ws_size >= off) {
        // -------- CSR + gather path --------
        // zero graph_acc and deg (adjacent)
        hipMemsetAsync(graph_acc, 0, gaB + degB, stream);
        transpose_W<<<(H * H + 255) / 256, 256, 0, stream>>>(W, WtG);

        hist_kernel<<<nbE, 256, 0, stream>>>(i1, i2, deg, E);
        scan_partials<<<NBS, 256, 0, stream>>>(deg, chunk, N);
        scan_offsets<<<1, 64, 0, stream>>>(chunk, NBS);
        scan_final<<<NBS, 256, 0, stream>>>(deg, chunk, row_ptr, pos, N);
        fill_kernel<<<nbE, 256, 0, stream>>>(i1, i2, pos, adj, E);

        gather_nodes<<<(N + 3) / 4, 256, 0, stream>>>(
            a1, a2, e0, adj, row_ptr, deg, x, N, E);

        node_transform<<<(N + NPB - 1) / NPB, 256, 0, stream>>>(
            x, nullptr, batch, WtG, b, graph_acc, N);
    } else {
        // -------- fallback: atomic scatter path --------
        hipMemsetAsync(x, 0, xB + gaB, stream);   // x doubles as node_acc; graph_acc follows
        transpose_W<<<(H * H + 255) / 256, 256, 0, stream>>>(W, WtG);
        long long totB = 2LL * E * 32;
        int nbB = (int)((totB + 255) / 256);
        scatter_edges<<<nbB, 256, 0, stream>>>(a1, a2, i1, i2, x, E);
        node_transform<<<(N + NPB - 1) / NPB, 256, 0, stream>>>(
            x, e0, batch, WtG, b, graph_acc, N);
    }

    finalize<<<(NGRAPH * H + 255) / 256, 256, 0, stream>>>(graph_acc, batch, out, N);
}

// Round 5
// 847.311 us; speedup vs baseline: 1.6809x; 1.1034x over previous
//
#include <hip/hip_runtime.h>
#include <hip/hip_bf16.h>

#define H 128
#define NGRAPH 512
#define NPB 32   // nodes per block in gather_transform

// ================= CSR build =================

__global__ __launch_bounds__(256) void hist_kernel(
    const int* __restrict__ i1, const int* __restrict__ i2,
    int* __restrict__ deg, int E)
{
    int g = blockIdx.x * 256 + threadIdx.x;
    int e = g * 4;
    if (e + 4 <= E) {
        int4 a = *(const int4*)(i1 + e);
        int4 b = *(const int4*)(i2 + e);
        atomicAdd(&deg[a.x], 1); atomicAdd(&deg[a.y], 1);
        atomicAdd(&deg[a.z], 1); atomicAdd(&deg[a.w], 1);
        atomicAdd(&deg[b.x], 1); atomicAdd(&deg[b.y], 1);
        atomicAdd(&deg[b.z], 1); atomicAdd(&deg[b.w], 1);
    } else if (e < E) {
        for (int k = e; k < E; ++k) {
            atomicAdd(&deg[i1[k]], 1);
            atomicAdd(&deg[i2[k]], 1);
        }
    }
}

__global__ __launch_bounds__(256) void scan_partials(
    const int* __restrict__ deg, int* __restrict__ partial, int N)
{
    __shared__ int s[256];
    int t = threadIdx.x;
    int i = blockIdx.x * 256 + t;
    s[t] = (i < N) ? deg[i] : 0;
    __syncthreads();
    for (int off = 128; off > 0; off >>= 1) {
        if (t < off) s[t] += s[t + off];
        __syncthreads();
    }
    if (t == 0) partial[blockIdx.x] = s[0];
}

// exclusive scan of up to 1024 partials in one block (serial fallback beyond)
__global__ __launch_bounds__(1024) void scan_offsets(int* __restrict__ partial, int nb)
{
    if (nb > 1024) {
        if (threadIdx.x == 0) {
            int run = 0;
            for (int i = 0; i < nb; ++i) { int v = partial[i]; partial[i] = run; run += v; }
        }
        return;
    }
    __shared__ int s[1024];
    int t = threadIdx.x;
    int v = (t < nb) ? partial[t] : 0;
    s[t] = v;
    __syncthreads();
    for (int off = 1; off < 1024; off <<= 1) {
        int tmp = (t >= off) ? s[t - off] : 0;
        __syncthreads();
        s[t] += tmp;
        __syncthreads();
    }
    if (t < nb) partial[t] = s[t] - v;   // exclusive
}

__global__ __launch_bounds__(256) void scan_final(
    const int* __restrict__ deg, const int* __restrict__ partial,
    int* __restrict__ row_ptr, int* __restrict__ pos, int N)
{
    __shared__ int s[256];
    int t = threadIdx.x;
    int i = blockIdx.x * 256 + t;
    int v = (i < N) ? deg[i] : 0;
    s[t] = v;
    __syncthreads();
    for (int off = 1; off < 256; off <<= 1) {
        int tmp = (t >= off) ? s[t - off] : 0;
        __syncthreads();
        s[t] += tmp;
        __syncthreads();
    }
    if (i < N) {
        int excl = partial[blockIdx.x] + s[t] - v;
        row_ptr[i] = excl;
        pos[i] = excl;
    }
}

__global__ __launch_bounds__(256) void fill_kernel(
    const int* __restrict__ i1, const int* __restrict__ i2,
    int* __restrict__ pos, int* __restrict__ adj, int E)
{
    int g = blockIdx.x * 256 + threadIdx.x;
    int e = g * 4;
    if (e + 4 <= E) {
        int4 a = *(const int4*)(i1 + e);
        int4 b = *(const int4*)(i2 + e);
        int s;
        s = atomicAdd(&pos[a.x], 1); adj[s] = e + 0;
        s = atomicAdd(&pos[a.y], 1); adj[s] = e + 1;
        s = atomicAdd(&pos[a.z], 1); adj[s] = e + 2;
        s = atomicAdd(&pos[a.w], 1); adj[s] = e + 3;
        s = atomicAdd(&pos[b.x], 1); adj[s] = E + e + 0;
        s = atomicAdd(&pos[b.y], 1); adj[s] = E + e + 1;
        s = atomicAdd(&pos[b.z], 1); adj[s] = E + e + 2;
        s = atomicAdd(&pos[b.w], 1); adj[s] = E + e + 3;
    } else if (e < E) {
        for (int k = e; k < E; ++k) {
            int s1 = atomicAdd(&pos[i1[k]], 1); adj[s1] = k;
            int s2 = atomicAdd(&pos[i2[k]], 1); adj[s2] = E + k;
        }
    }
}

// ================= W transpose =================
__global__ __launch_bounds__(256) void transpose_W(
    const float* __restrict__ W, float* __restrict__ WtG)
{
    int i = blockIdx.x * 256 + threadIdx.x;
    int j = i >> 7, k = i & (H - 1);
    WtG[k * H + j] = W[j * H + k];
}

// ======= fused: gather edges -> LDS, Linear+ELU, pooled atomic add =======
// block = 32 nodes, 256 threads (4 waves). Wave w gathers nodes w*8..w*8+7:
// lane owns features {2*lane, 2*lane+1}; each edge row read is a contiguous
// 512B wave transaction; register accumulate; add e0; write transposed LDS.
// Then 4x4-register-tile GEMM vs WtG, ELU, run-length-compressed graph atomics.
__global__ __launch_bounds__(256) void gather_transform(
    const float* __restrict__ a1, const float* __restrict__ a2,
    const float* __restrict__ e0, const int* __restrict__ adj,
    const int* __restrict__ row_ptr, const int* __restrict__ deg,
    const int* __restrict__ batch, const float* __restrict__ WtG,
    const float* __restrict__ bias, float* __restrict__ graph_acc,
    int N, int E)
{
    __shared__ __align__(16) float xsT[H * 36];  // [k][n], row stride 36
    __shared__ int bs[NPB];

    int t = threadIdx.x, wave = t >> 6, lane = t & 63;
    int node0 = blockIdx.x * NPB;

    if (t < NPB) {
        int gn = node0 + t;
        bs[t] = (gn < N) ? batch[gn] : -1;
    }

    #pragma unroll
    for (int j = 0; j < 8; ++j) {
        int nl = wave * 8 + j;
        int gn = node0 + nl;
        float ax = 0.f, ay = 0.f;
        if (gn < N) {
            int start = row_ptr[gn], d = deg[gn];
            int i = 0;
            for (; i + 4 <= d; i += 4) {
                int t0 = adj[start + i + 0], t1 = adj[start + i + 1];
                int t2 = adj[start + i + 2], t3 = adj[start + i + 3];
                const float* p0 = (t0 < E) ? a1 + (size_t)t0 * H : a2 + (size_t)(t0 - E) * H;
                const float* p1 = (t1 < E) ? a1 + (size_t)t1 * H : a2 + (size_t)(t1 - E) * H;
                const float* p2 = (t2 < E) ? a1 + (size_t)t2 * H : a2 + (size_t)(t2 - E) * H;
                const float* p3 = (t3 < E) ? a1 + (size_t)t3 * H : a2 + (size_t)(t3 - E) * H;
                float2 v0 = *(const float2*)(p0 + lane * 2);
                float2 v1 = *(const float2*)(p1 + lane * 2);
                float2 v2 = *(const float2*)(p2 + lane * 2);
                float2 v3 = *(const float2*)(p3 + lane * 2);
                ax += v0.x + v1.x + v2.x + v3.x;
                ay += v0.y + v1.y + v2.y + v3.y;
            }
            for (; i < d; ++i) {
                int t0 = adj[start + i];
                const float* p0 = (t0 < E) ? a1 + (size_t)t0 * H : a2 + (size_t)(t0 - E) * H;
                float2 v0 = *(const float2*)(p0 + lane * 2);
                ax += v0.x; ay += v0.y;
            }
            size_t o = (size_t)gn * H + lane * 2;
            float2 ev = *(const float2*)(e0 + o);
            ax += ev.x; ay += ev.y;
        }
        xsT[(2 * lane + 0) * 36 + nl] = ax;
        xsT[(2 * lane + 1) * 36 + nl] = ay;
    }
    __syncthreads();

    int n0 = (t & 7) * 4;
    int j0 = (t >> 3) * 4;

    float acc[4][4] = {};
    #pragma unroll 4
    for (int k = 0; k < H; ++k) {
        float xr[4], wr[4];
        *(float4*)xr = *(const float4*)&xsT[k * 36 + n0];
        *(float4*)wr = *(const float4*)&WtG[k * H + j0];
        #pragma unroll
        for (int nn = 0; nn < 4; ++nn)
            #pragma unroll
            for (int jj = 0; jj < 4; ++jj)
                acc[nn][jj] = fmaf(xr[nn], wr[jj], acc[nn][jj]);
    }

    float bj[4];
    *(float4*)bj = *(const float4*)&bias[j0];

    #pragma unroll
    for (int jj = 0; jj < 4; ++jj) {
        int j = j0 + jj;
        int curg = -1; float s = 0.f;
        #pragma unroll
        for (int nn = 0; nn < 4; ++nn) {
            int g = bs[n0 + nn];
            if (g < 0) continue;
            float a = acc[nn][jj] + bj[jj];
            float y = (a > 0.f) ? a : expm1f(a);
            if (g == curg) { s += y; }
            else {
                if (curg >= 0) unsafeAtomicAdd(&graph_acc[curg * H + j], s);
                curg = g; s = y;
            }
        }
        if (curg >= 0) unsafeAtomicAdd(&graph_acc[curg * H + j], s);
    }
}

// ================= finalize: divide by per-graph counts =================
__device__ __forceinline__ int lower_bound_dev(const int* __restrict__ b, int n, int v) {
    int lo = 0, hi = n;
    while (lo < hi) { int m = (lo + hi) >> 1; if (b[m] < v) lo = m + 1; else hi = m; }
    return lo;
}

__global__ __launch_bounds__(256) void finalize(
    const float* __restrict__ graph_acc, const int* __restrict__ batch,
    float* __restrict__ out, int N)
{
    int i = blockIdx.x * 256 + threadIdx.x;
    if (i >= NGRAPH * H) return;
    int g = i >> 7;
    int lo = lower_bound_dev(batch, N, g);
    int hi = lower_bound_dev(batch, N, g + 1);
    float c = fmaxf((float)(hi - lo), 1.0f);
    out[i] = graph_acc[i] / c;
}

extern "C" void kernel_launch(void* const* d_in, const int* in_sizes, int n_in,
                              void* d_out, int out_size, void* d_ws, size_t ws_size,
                              hipStream_t stream)
{
    const float* e0    = (const float*)d_in[0];
    const float* a1    = (const float*)d_in[1];
    const float* a2    = (const float*)d_in[2];
    const int*   i1    = (const int*)d_in[3];
    const int*   i2    = (const int*)d_in[4];
    const int*   batch = (const int*)d_in[5];
    const float* W     = (const float*)d_in[7];
    const float* b     = (const float*)d_in[8];
    float* out = (float*)d_out;

    int N = in_sizes[0] / H;
    int E = in_sizes[3];
    int NBS = (N + 255) / 256;              // scan chunks

    auto align16 = [](size_t v) { return (v + 15) & ~(size_t)15; };

    char* ws = (char*)d_ws;
    size_t gaB   = align16((size_t)NGRAPH * H * sizeof(float));
    size_t degB  = align16((size_t)N * sizeof(int));
    size_t rowB  = degB, posB = degB;
    size_t chB   = align16((size_t)NBS * sizeof(int));
    size_t wtB   = align16((size_t)H * H * sizeof(float));
    size_t adjB  = align16((size_t)2 * E * sizeof(int));

    size_t off = 0;
    float* graph_acc = (float*)(ws + off); off += gaB;
    int*   deg       = (int*)  (ws + off); off += degB;
    int*   row_ptr   = (int*)  (ws + off); off += rowB;
    int*   pos       = (int*)  (ws + off); off += posB;
    int*   chunk     = (int*)  (ws + off); off += chB;
    float* WtG       = (float*)(ws + off); off += wtB;
    int*   adj       = (int*)  (ws + off); off += adjB;
    (void)ws_size;

    // zero graph_acc and deg (adjacent in ws)
    hipMemsetAsync(graph_acc, 0, gaB + degB, stream);
    transpose_W<<<(H * H + 255) / 256, 256, 0, stream>>>(W, WtG);

    int nbE4 = (E / 4 + 255) / 256 + 1;   // 4 edges per thread (+1 covers tail)
    hist_kernel<<<nbE4, 256, 0, stream>>>(i1, i2, deg, E);
    scan_partials<<<NBS, 256, 0, stream>>>(deg, chunk, N);
    scan_offsets<<<1, 1024, 0, stream>>>(chunk, NBS);
    scan_final<<<NBS, 256, 0, stream>>>(deg, chunk, row_ptr, pos, N);
    fill_kernel<<<nbE4, 256, 0, stream>>>(i1, i2, pos, adj, E);

    gather_transform<<<(N + NPB - 1) / NPB, 256, 0, stream>>>(
        a1, a2, e0, adj, row_ptr, deg, batch, WtG, b, graph_acc, N, E);

    finalize<<<(NGRAPH * H + 255) / 256, 256, 0, stream>>>(graph_acc, batch, out, N);
}

// Round 6
// 845.457 us; speedup vs baseline: 1.6845x; 1.0022x over previous
//
#include <hip/hip_runtime.h>
#include <hip/hip_bf16.h>

#define H 128
#define NGRAPH 512
#define NPB 32   // nodes per block in gather_transform

typedef float v2f __attribute__((ext_vector_type(2)));

// ================= CSR build =================

__global__ __launch_bounds__(256) void hist_kernel(
    const int* __restrict__ i1, const int* __restrict__ i2,
    int* __restrict__ deg, int E)
{
    int g = blockIdx.x * 256 + threadIdx.x;
    int e = g * 4;
    if (e + 4 <= E) {
        int4 a = *(const int4*)(i1 + e);
        int4 b = *(const int4*)(i2 + e);
        atomicAdd(&deg[a.x], 1); atomicAdd(&deg[a.y], 1);
        atomicAdd(&deg[a.z], 1); atomicAdd(&deg[a.w], 1);
        atomicAdd(&deg[b.x], 1); atomicAdd(&deg[b.y], 1);
        atomicAdd(&deg[b.z], 1); atomicAdd(&deg[b.w], 1);
    } else if (e < E) {
        for (int k = e; k < E; ++k) {
            atomicAdd(&deg[i1[k]], 1);
            atomicAdd(&deg[i2[k]], 1);
        }
    }
}

__global__ __launch_bounds__(256) void scan_partials(
    const int* __restrict__ deg, int* __restrict__ partial, int N)
{
    __shared__ int s[256];
    int t = threadIdx.x;
    int i = blockIdx.x * 256 + t;
    s[t] = (i < N) ? deg[i] : 0;
    __syncthreads();
    for (int off = 128; off > 0; off >>= 1) {
        if (t < off) s[t] += s[t + off];
        __syncthreads();
    }
    if (t == 0) partial[blockIdx.x] = s[0];
}

// exclusive scan of up to 1024 partials in one block (serial fallback beyond)
__global__ __launch_bounds__(1024) void scan_offsets(int* __restrict__ partial, int nb)
{
    if (nb > 1024) {
        if (threadIdx.x == 0) {
            int run = 0;
            for (int i = 0; i < nb; ++i) { int v = partial[i]; partial[i] = run; run += v; }
        }
        return;
    }
    __shared__ int s[1024];
    int t = threadIdx.x;
    int v = (t < nb) ? partial[t] : 0;
    s[t] = v;
    __syncthreads();
    for (int off = 1; off < 1024; off <<= 1) {
        int tmp = (t >= off) ? s[t - off] : 0;
        __syncthreads();
        s[t] += tmp;
        __syncthreads();
    }
    if (t < nb) partial[t] = s[t] - v;   // exclusive
}

__global__ __launch_bounds__(256) void scan_final(
    const int* __restrict__ deg, const int* __restrict__ partial,
    int* __restrict__ row_ptr, int* __restrict__ pos, int N)
{
    __shared__ int s[256];
    int t = threadIdx.x;
    int i = blockIdx.x * 256 + t;
    int v = (i < N) ? deg[i] : 0;
    s[t] = v;
    __syncthreads();
    for (int off = 1; off < 256; off <<= 1) {
        int tmp = (t >= off) ? s[t - off] : 0;
        __syncthreads();
        s[t] += tmp;
        __syncthreads();
    }
    if (i < N) {
        int excl = partial[blockIdx.x] + s[t] - v;
        row_ptr[i] = excl;
        pos[i] = excl;
    }
}

__global__ __launch_bounds__(256) void fill_kernel(
    const int* __restrict__ i1, const int* __restrict__ i2,
    int* __restrict__ pos, int* __restrict__ adj, int E)
{
    int g = blockIdx.x * 256 + threadIdx.x;
    int e = g * 4;
    if (e + 4 <= E) {
        int4 a = *(const int4*)(i1 + e);
        int4 b = *(const int4*)(i2 + e);
        int s;
        s = atomicAdd(&pos[a.x], 1); adj[s] = e + 0;
        s = atomicAdd(&pos[a.y], 1); adj[s] = e + 1;
        s = atomicAdd(&pos[a.z], 1); adj[s] = e + 2;
        s = atomicAdd(&pos[a.w], 1); adj[s] = e + 3;
        s = atomicAdd(&pos[b.x], 1); adj[s] = E + e + 0;
        s = atomicAdd(&pos[b.y], 1); adj[s] = E + e + 1;
        s = atomicAdd(&pos[b.z], 1); adj[s] = E + e + 2;
        s = atomicAdd(&pos[b.w], 1); adj[s] = E + e + 3;
    } else if (e < E) {
        for (int k = e; k < E; ++k) {
            int s1 = atomicAdd(&pos[i1[k]], 1); adj[s1] = k;
            int s2 = atomicAdd(&pos[i2[k]], 1); adj[s2] = E + k;
        }
    }
}

// ================= W transpose =================
__global__ __launch_bounds__(256) void transpose_W(
    const float* __restrict__ W, float* __restrict__ WtG)
{
    int i = blockIdx.x * 256 + threadIdx.x;
    int j = i >> 7, k = i & (H - 1);
    WtG[k * H + j] = W[j * H + k];
}

// edge-row load: 512B per wave, non-temporal (zero reuse -> keep L2 clean)
__device__ __forceinline__ v2f row_load(
    const float* __restrict__ a1, const float* __restrict__ a2,
    int t, int E, int lane)
{
    const float* p = (t < E) ? a1 + (size_t)t * H : a2 + (size_t)(t - E) * H;
    return __builtin_nontemporal_load((const v2f*)(p + lane * 2));
}

// ======= fused: gather edges -> LDS, Linear+ELU, pooled atomic add =======
// block = 32 nodes, 256 threads (4 waves). Wave w gathers nodes w*8..w*8+7
// with an 8-row ping-pong pipeline (two quads in flight); lane owns features
// {2*lane, 2*lane+1}. Then 4x4-register-tile GEMM vs WtG, ELU, run-length-
// compressed graph atomics.
__global__ __launch_bounds__(256) void gather_transform(
    const float* __restrict__ a1, const float* __restrict__ a2,
    const float* __restrict__ e0, const int* __restrict__ adj,
    const int* __restrict__ row_ptr, const int* __restrict__ deg,
    const int* __restrict__ batch, const float* __restrict__ WtG,
    const float* __restrict__ bias, float* __restrict__ graph_acc,
    int N, int E)
{
    __shared__ __align__(16) float xsT[H * 36];  // [k][n], row stride 36
    __shared__ int bs[NPB];

    int t = threadIdx.x, wave = t >> 6, lane = t & 63;
    int node0 = blockIdx.x * NPB;

    if (t < NPB) {
        int gn = node0 + t;
        bs[t] = (gn < N) ? batch[gn] : -1;
    }

    #pragma unroll
    for (int j = 0; j < 8; ++j) {
        int nl = wave * 8 + j;
        int gn = node0 + nl;
        float ax = 0.f, ay = 0.f;
        if (gn < N) {
            int start = row_ptr[gn], d = deg[gn];
            int d8 = d & ~7;
            int i = 0;
            if (d8) {
                v2f A0, A1, A2, A3, B0, B1, B2, B3;
                {
                    int u0 = adj[start + 0], u1 = adj[start + 1];
                    int u2 = adj[start + 2], u3 = adj[start + 3];
                    A0 = row_load(a1, a2, u0, E, lane);
                    A1 = row_load(a1, a2, u1, E, lane);
                    A2 = row_load(a1, a2, u2, E, lane);
                    A3 = row_load(a1, a2, u3, E, lane);
                    int w0 = adj[start + 4], w1 = adj[start + 5];
                    int w2 = adj[start + 6], w3 = adj[start + 7];
                    B0 = row_load(a1, a2, w0, E, lane);
                    B1 = row_load(a1, a2, w1, E, lane);
                    B2 = row_load(a1, a2, w2, E, lane);
                    B3 = row_load(a1, a2, w3, E, lane);
                }
                for (i = 8; i < d8; i += 8) {
                    ax += A0.x + A1.x + A2.x + A3.x;
                    ay += A0.y + A1.y + A2.y + A3.y;
                    {
                        int u0 = adj[start + i + 0], u1 = adj[start + i + 1];
                        int u2 = adj[start + i + 2], u3 = adj[start + i + 3];
                        A0 = row_load(a1, a2, u0, E, lane);
                        A1 = row_load(a1, a2, u1, E, lane);
                        A2 = row_load(a1, a2, u2, E, lane);
                        A3 = row_load(a1, a2, u3, E, lane);
                    }
                    ax += B0.x + B1.x + B2.x + B3.x;
                    ay += B0.y + B1.y + B2.y + B3.y;
                    {
                        int w0 = adj[start + i + 4], w1 = adj[start + i + 5];
                        int w2 = adj[start + i + 6], w3 = adj[start + i + 7];
                        B0 = row_load(a1, a2, w0, E, lane);
                        B1 = row_load(a1, a2, w1, E, lane);
                        B2 = row_load(a1, a2, w2, E, lane);
                        B3 = row_load(a1, a2, w3, E, lane);
                    }
                }
                ax += A0.x + A1.x + A2.x + A3.x;
                ay += A0.y + A1.y + A2.y + A3.y;
                ax += B0.x + B1.x + B2.x + B3.x;
                ay += B0.y + B1.y + B2.y + B3.y;
                i = d8;
            }
            if (i + 4 <= d) {
                int u0 = adj[start + i + 0], u1 = adj[start + i + 1];
                int u2 = adj[start + i + 2], u3 = adj[start + i + 3];
                v2f v0 = row_load(a1, a2, u0, E, lane);
                v2f v1 = row_load(a1, a2, u1, E, lane);
                v2f v2 = row_load(a1, a2, u2, E, lane);
                v2f v3 = row_load(a1, a2, u3, E, lane);
                ax += v0.x + v1.x + v2.x + v3.x;
                ay += v0.y + v1.y + v2.y + v3.y;
                i += 4;
            }
            for (; i < d; ++i) {
                int u0 = adj[start + i];
                v2f v0 = row_load(a1, a2, u0, E, lane);
                ax += v0.x; ay += v0.y;
            }
            size_t o = (size_t)gn * H + lane * 2;
            v2f ev = __builtin_nontemporal_load((const v2f*)(e0 + o));
            ax += ev.x; ay += ev.y;
        }
        xsT[(2 * lane + 0) * 36 + nl] = ax;
        xsT[(2 * lane + 1) * 36 + nl] = ay;
    }
    __syncthreads();

    int n0 = (t & 7) * 4;
    int j0 = (t >> 3) * 4;

    float acc[4][4] = {};
    #pragma unroll 4
    for (int k = 0; k < H; ++k) {
        float xr[4], wr[4];
        *(float4*)xr = *(const float4*)&xsT[k * 36 + n0];
        *(float4*)wr = *(const float4*)&WtG[k * H + j0];
        #pragma unroll
        for (int nn = 0; nn < 4; ++nn)
            #pragma unroll
            for (int jj = 0; jj < 4; ++jj)
                acc[nn][jj] = fmaf(xr[nn], wr[jj], acc[nn][jj]);
    }

    float bj[4];
    *(float4*)bj = *(const float4*)&bias[j0];

    #pragma unroll
    for (int jj = 0; jj < 4; ++jj) {
        int j = j0 + jj;
        int curg = -1; float s = 0.f;
        #pragma unroll
        for (int nn = 0; nn < 4; ++nn) {
            int g = bs[n0 + nn];
            if (g < 0) continue;
            float a = acc[nn][jj] + bj[jj];
            float y = (a > 0.f) ? a : expm1f(a);
            if (g == curg) { s += y; }
            else {
                if (curg >= 0) unsafeAtomicAdd(&graph_acc[curg * H + j], s);
                curg = g; s = y;
            }
        }
        if (curg >= 0) unsafeAtomicAdd(&graph_acc[curg * H + j], s);
    }
}

// ================= finalize: divide by per-graph counts =================
__device__ __forceinline__ int lower_bound_dev(const int* __restrict__ b, int n, int v) {
    int lo = 0, hi = n;
    while (lo < hi) { int m = (lo + hi) >> 1; if (b[m] < v) lo = m + 1; else hi = m; }
    return lo;
}

__global__ __launch_bounds__(256) void finalize(
    const float* __restrict__ graph_acc, const int* __restrict__ batch,
    float* __restrict__ out, int N)
{
    int i = blockIdx.x * 256 + threadIdx.x;
    if (i >= NGRAPH * H) return;
    int g = i >> 7;
    int lo = lower_bound_dev(batch, N, g);
    int hi = lower_bound_dev(batch, N, g + 1);
    float c = fmaxf((float)(hi - lo), 1.0f);
    out[i] = graph_acc[i] / c;
}

extern "C" void kernel_launch(void* const* d_in, const int* in_sizes, int n_in,
                              void* d_out, int out_size, void* d_ws, size_t ws_size,
                              hipStream_t stream)
{
    const float* e0    = (const float*)d_in[0];
    const float* a1    = (const float*)d_in[1];
    const float* a2    = (const float*)d_in[2];
    const int*   i1    = (const int*)d_in[3];
    const int*   i2    = (const int*)d_in[4];
    const int*   batch = (const int*)d_in[5];
    const float* W     = (const float*)d_in[7];
    const float* b     = (const float*)d_in[8];
    float* out = (float*)d_out;

    int N = in_sizes[0] / H;
    int E = in_sizes[3];
    int NBS = (N + 255) / 256;              // scan chunks

    auto align16 = [](size_t v) { return (v + 15) & ~(size_t)15; };

    char* ws = (char*)d_ws;
    size_t gaB   = align16((size_t)NGRAPH * H * sizeof(float));
    size_t degB  = align16((size_t)N * sizeof(int));
    size_t rowB  = degB, posB = degB;
    size_t chB   = align16((size_t)NBS * sizeof(int));
    size_t wtB   = align16((size_t)H * H * sizeof(float));
    size_t adjB  = align16((size_t)2 * E * sizeof(int));

    size_t off = 0;
    float* graph_acc = (float*)(ws + off); off += gaB;
    int*   deg       = (int*)  (ws + off); off += degB;
    int*   row_ptr   = (int*)  (ws + off); off += rowB;
    int*   pos       = (int*)  (ws + off); off += posB;
    int*   chunk     = (int*)  (ws + off); off += chB;
    float* WtG       = (float*)(ws + off); off += wtB;
    int*   adj       = (int*)  (ws + off); off += adjB;
    (void)ws_size;

    // zero graph_acc and deg (adjacent in ws)
    hipMemsetAsync(graph_acc, 0, gaB + degB, stream);
    transpose_W<<<(H * H + 255) / 256, 256, 0, stream>>>(W, WtG);

    int nbE4 = (E / 4 + 255) / 256 + 1;   // 4 edges per thread (+1 covers tail)
    hist_kernel<<<nbE4, 256, 0, stream>>>(i1, i2, deg, E);
    scan_partials<<<NBS, 256, 0, stream>>>(deg, chunk, N);
    scan_offsets<<<1, 1024, 0, stream>>>(chunk, NBS);
    scan_final<<<NBS, 256, 0, stream>>>(deg, chunk, row_ptr, pos, N);
    fill_kernel<<<nbE4, 256, 0, stream>>>(i1, i2, pos, adj, E);

    gather_transform<<<(N + NPB - 1) / NPB, 256, 0, stream>>>(
        a1, a2, e0, adj, row_ptr, deg, batch, WtG, b, graph_acc, N, E);

    finalize<<<(NGRAPH * H + 255) / 256, 256, 0, stream>>>(graph_acc, batch, out, N);
}

// Round 7
// 843.031 us; speedup vs baseline: 1.6894x; 1.0029x over previous
//
#include <hip/hip_runtime.h>
#include <hip/hip_bf16.h>

#define H 128
#define NGRAPH 512
#define NPB 32   // nodes per block in gather_transform

typedef float v4f __attribute__((ext_vector_type(4)));
typedef unsigned long long ull;

// ================= CSR build =================

__global__ __launch_bounds__(256) void hist_kernel(
    const int* __restrict__ i1, const int* __restrict__ i2,
    int* __restrict__ deg, int E)
{
    int g = blockIdx.x * 256 + threadIdx.x;
    int e = g * 4;
    if (e + 4 <= E) {
        int4 a = *(const int4*)(i1 + e);
        int4 b = *(const int4*)(i2 + e);
        atomicAdd(&deg[a.x], 1); atomicAdd(&deg[a.y], 1);
        atomicAdd(&deg[a.z], 1); atomicAdd(&deg[a.w], 1);
        atomicAdd(&deg[b.x], 1); atomicAdd(&deg[b.y], 1);
        atomicAdd(&deg[b.z], 1); atomicAdd(&deg[b.w], 1);
    } else if (e < E) {
        for (int k = e; k < E; ++k) {
            atomicAdd(&deg[i1[k]], 1);
            atomicAdd(&deg[i2[k]], 1);
        }
    }
}

__global__ __launch_bounds__(256) void scan_partials(
    const int* __restrict__ deg, int* __restrict__ partial, int N)
{
    __shared__ int s[256];
    int t = threadIdx.x;
    int i = blockIdx.x * 256 + t;
    s[t] = (i < N) ? deg[i] : 0;
    __syncthreads();
    for (int off = 128; off > 0; off >>= 1) {
        if (t < off) s[t] += s[t + off];
        __syncthreads();
    }
    if (t == 0) partial[blockIdx.x] = s[0];
}

// exclusive scan of up to 1024 partials in one block (serial fallback beyond)
__global__ __launch_bounds__(1024) void scan_offsets(int* __restrict__ partial, int nb)
{
    if (nb > 1024) {
        if (threadIdx.x == 0) {
            int run = 0;
            for (int i = 0; i < nb; ++i) { int v = partial[i]; partial[i] = run; run += v; }
        }
        return;
    }
    __shared__ int s[1024];
    int t = threadIdx.x;
    int v = (t < nb) ? partial[t] : 0;
    s[t] = v;
    __syncthreads();
    for (int off = 1; off < 1024; off <<= 1) {
        int tmp = (t >= off) ? s[t - off] : 0;
        __syncthreads();
        s[t] += tmp;
        __syncthreads();
    }
    if (t < nb) partial[t] = s[t] - v;   // exclusive
}

__global__ __launch_bounds__(256) void scan_final(
    const int* __restrict__ deg, const int* __restrict__ partial,
    int* __restrict__ row_ptr, int* __restrict__ pos, int N)
{
    __shared__ int s[256];
    int t = threadIdx.x;
    int i = blockIdx.x * 256 + t;
    int v = (i < N) ? deg[i] : 0;
    s[t] = v;
    __syncthreads();
    for (int off = 1; off < 256; off <<= 1) {
        int tmp = (t >= off) ? s[t - off] : 0;
        __syncthreads();
        s[t] += tmp;
        __syncthreads();
    }
    if (i < N) {
        int excl = partial[blockIdx.x] + s[t] - v;
        row_ptr[i] = excl;
        pos[i] = excl;
        if (i == N - 1) row_ptr[N] = excl + v;   // sentinel: total 2E
    }
}

// fill stores the PRECOMPUTED row base address (a1/a2 resolved here, once)
__global__ __launch_bounds__(256) void fill_kernel(
    const int* __restrict__ i1, const int* __restrict__ i2,
    int* __restrict__ pos, ull* __restrict__ adjA,
    const float* __restrict__ a1, const float* __restrict__ a2, int E)
{
    int g = blockIdx.x * 256 + threadIdx.x;
    int e = g * 4;
    if (e + 4 <= E) {
        int4 a = *(const int4*)(i1 + e);
        int4 b = *(const int4*)(i2 + e);
        int s;
        s = atomicAdd(&pos[a.x], 1); adjA[s] = (ull)(a1 + (size_t)(e + 0) * H);
        s = atomicAdd(&pos[a.y], 1); adjA[s] = (ull)(a1 + (size_t)(e + 1) * H);
        s = atomicAdd(&pos[a.z], 1); adjA[s] = (ull)(a1 + (size_t)(e + 2) * H);
        s = atomicAdd(&pos[a.w], 1); adjA[s] = (ull)(a1 + (size_t)(e + 3) * H);
        s = atomicAdd(&pos[b.x], 1); adjA[s] = (ull)(a2 + (size_t)(e + 0) * H);
        s = atomicAdd(&pos[b.y], 1); adjA[s] = (ull)(a2 + (size_t)(e + 1) * H);
        s = atomicAdd(&pos[b.z], 1); adjA[s] = (ull)(a2 + (size_t)(e + 2) * H);
        s = atomicAdd(&pos[b.w], 1); adjA[s] = (ull)(a2 + (size_t)(e + 3) * H);
    } else if (e < E) {
        for (int k = e; k < E; ++k) {
            int s1 = atomicAdd(&pos[i1[k]], 1); adjA[s1] = (ull)(a1 + (size_t)k * H);
            int s2 = atomicAdd(&pos[i2[k]], 1); adjA[s2] = (ull)(a2 + (size_t)k * H);
        }
    }
}

// ================= W transpose =================
__global__ __launch_bounds__(256) void transpose_W(
    const float* __restrict__ W, float* __restrict__ WtG)
{
    int i = blockIdx.x * 256 + threadIdx.x;
    int j = i >> 7, k = i & (H - 1);
    WtG[k * H + j] = W[j * H + k];
}

// paired row load: lanes 0-31 <- row 2k, lanes 32-63 <- row 2k+1 (float4/lane)
__device__ __forceinline__ v4f prow(const ull* __restrict__ ap, int k,
                                    int half, ull loff)
{
    ull a0 = ap[2 * k], a1 = ap[2 * k + 1];
    ull a = half ? a1 : a0;
    return __builtin_nontemporal_load((const v4f*)(a + loff));
}

// ======= fused: gather edges -> LDS, Linear+ELU, pooled atomic add =======
// block = 32 nodes, 256 threads (4 waves); wave w owns nodes w*8..w*8+7.
// Rows consumed 2-at-a-time (1KB per wave-load), v_pk_add_f32 accumulate,
// cross-half shfl reduce, then 4x4-register-tile GEMM vs WtG, ELU,
// run-length-compressed graph atomics.
__global__ __launch_bounds__(256) void gather_transform(
    const float* __restrict__ e0, const ull* __restrict__ adjA,
    const int* __restrict__ row_ptr, const int* __restrict__ batch,
    const float* __restrict__ WtG, const float* __restrict__ bias,
    float* __restrict__ graph_acc, int N)
{
    __shared__ __align__(16) float xsT[H * 36];  // [k][n], row stride 36
    __shared__ int bs[NPB];

    int t = threadIdx.x, wave = t >> 6, lane = t & 63;
    int half = lane >> 5;
    ull loff = (ull)(lane & 31) * 16;
    int node0 = blockIdx.x * NPB;

    if (t < NPB) {
        int gn = node0 + t;
        bs[t] = (gn < N) ? batch[gn] : -1;
    }

    #pragma unroll
    for (int j = 0; j < 8; ++j) {
        int nl = wave * 8 + j;
        int gn = node0 + nl;
        v4f acc0 = {0.f, 0.f, 0.f, 0.f}, acc1 = {0.f, 0.f, 0.f, 0.f};
        if (gn < N) {
            int start = row_ptr[gn];
            int d = row_ptr[gn + 1] - start;
            const ull* ap = adjA + start;
            int np = d >> 1;          // full pairs
            int k = 0;
            int np4 = np & ~3;
            if (np4) {
                v4f A0 = prow(ap, 0, half, loff), A1 = prow(ap, 1, half, loff);
                v4f A2 = prow(ap, 2, half, loff), A3 = prow(ap, 3, half, loff);
                for (k = 4; k < np4; k += 4) {
                    acc0 += A0; A0 = prow(ap, k + 0, half, loff);
                    acc1 += A1; A1 = prow(ap, k + 1, half, loff);
                    acc0 += A2; A2 = prow(ap, k + 2, half, loff);
                    acc1 += A3; A3 = prow(ap, k + 3, half, loff);
                }
                acc0 += A0; acc1 += A1; acc0 += A2; acc1 += A3;
                k = np4;
            }
            for (; k < np; ++k) acc0 += prow(ap, k, half, loff);
            if (d & 1) {               // tail row: both halves load it, mask upper
                ull a = ap[d - 1];
                v4f v = __builtin_nontemporal_load((const v4f*)(a + loff));
                if (half) v = (v4f){0.f, 0.f, 0.f, 0.f};
                acc0 += v;
            }
        }
        v4f acc = acc0 + acc1;
        float r0 = acc.x + __shfl_xor(acc.x, 32, 64);
        float r1 = acc.y + __shfl_xor(acc.y, 32, 64);
        float r2 = acc.z + __shfl_xor(acc.z, 32, 64);
        float r3 = acc.w + __shfl_xor(acc.w, 32, 64);
        if (half == 0) {
            v4f ev = {0.f, 0.f, 0.f, 0.f};
            if (gn < N)
                ev = *(const v4f*)(e0 + (size_t)gn * H + (lane & 31) * 4);
            int f0 = (lane & 31) * 4;
            xsT[(f0 + 0) * 36 + nl] = r0 + ev.x;
            xsT[(f0 + 1) * 36 + nl] = r1 + ev.y;
            xsT[(f0 + 2) * 36 + nl] = r2 + ev.z;
            xsT[(f0 + 3) * 36 + nl] = r3 + ev.w;
        }
    }
    __syncthreads();

    int n0 = (t & 7) * 4;
    int j0 = (t >> 3) * 4;

    float acc[4][4] = {};
    #pragma unroll 4
    for (int k = 0; k < H; ++k) {
        float xr[4], wr[4];
        *(float4*)xr = *(const float4*)&xsT[k * 36 + n0];
        *(float4*)wr = *(const float4*)&WtG[k * H + j0];
        #pragma unroll
        for (int nn = 0; nn < 4; ++nn)
            #pragma unroll
            for (int jj = 0; jj < 4; ++jj)
                acc[nn][jj] = fmaf(xr[nn], wr[jj], acc[nn][jj]);
    }

    float bj[4];
    *(float4*)bj = *(const float4*)&bias[j0];

    #pragma unroll
    for (int jj = 0; jj < 4; ++jj) {
        int j = j0 + jj;
        int curg = -1; float s = 0.f;
        #pragma unroll
        for (int nn = 0; nn < 4; ++nn) {
            int g = bs[n0 + nn];
            if (g < 0) continue;
            float a = acc[nn][jj] + bj[jj];
            float y = (a > 0.f) ? a : expm1f(a);
            if (g == curg) { s += y; }
            else {
                if (curg >= 0) unsafeAtomicAdd(&graph_acc[curg * H + j], s);
                curg = g; s = y;
            }
        }
        if (curg >= 0) unsafeAtomicAdd(&graph_acc[curg * H + j], s);
    }
}

// ================= finalize: divide by per-graph counts =================
__device__ __forceinline__ int lower_bound_dev(const int* __restrict__ b, int n, int v) {
    int lo = 0, hi = n;
    while (lo < hi) { int m = (lo + hi) >> 1; if (b[m] < v) lo = m + 1; else hi = m; }
    return lo;
}

__global__ __launch_bounds__(256) void finalize(
    const float* __restrict__ graph_acc, const int* __restrict__ batch,
    float* __restrict__ out, int N)
{
    int i = blockIdx.x * 256 + threadIdx.x;
    if (i >= NGRAPH * H) return;
    int g = i >> 7;
    int lo = lower_bound_dev(batch, N, g);
    int hi = lower_bound_dev(batch, N, g + 1);
    float c = fmaxf((float)(hi - lo), 1.0f);
    out[i] = graph_acc[i] / c;
}

extern "C" void kernel_launch(void* const* d_in, const int* in_sizes, int n_in,
                              void* d_out, int out_size, void* d_ws, size_t ws_size,
                              hipStream_t stream)
{
    const float* e0    = (const float*)d_in[0];
    const float* a1    = (const float*)d_in[1];
    const float* a2    = (const float*)d_in[2];
    const int*   i1    = (const int*)d_in[3];
    const int*   i2    = (const int*)d_in[4];
    const int*   batch = (const int*)d_in[5];
    const float* W     = (const float*)d_in[7];
    const float* b     = (const float*)d_in[8];
    float* out = (float*)d_out;

    int N = in_sizes[0] / H;
    int E = in_sizes[3];
    int NBS = (N + 255) / 256;              // scan chunks

    auto align16 = [](size_t v) { return (v + 15) & ~(size_t)15; };

    char* ws = (char*)d_ws;
    size_t gaB   = align16((size_t)NGRAPH * H * sizeof(float));
    size_t degB  = align16((size_t)N * sizeof(int));
    size_t rowB  = align16((size_t)(N + 1) * sizeof(int));
    size_t posB  = degB;
    size_t chB   = align16((size_t)NBS * sizeof(int));
    size_t wtB   = align16((size_t)H * H * sizeof(float));
    size_t adjB  = align16((size_t)2 * E * sizeof(ull));

    size_t off = 0;
    float* graph_acc = (float*)(ws + off); off += gaB;
    int*   deg       = (int*)  (ws + off); off += degB;
    int*   row_ptr   = (int*)  (ws + off); off += rowB;
    int*   pos       = (int*)  (ws + off); off += posB;
    int*   chunk     = (int*)  (ws + off); off += chB;
    float* WtG       = (float*)(ws + off); off += wtB;
    ull*   adjA      = (ull*)  (ws + off); off += adjB;
    (void)ws_size;

    // zero graph_acc and deg (adjacent in ws)
    hipMemsetAsync(graph_acc, 0, gaB + degB, stream);
    transpose_W<<<(H * H + 255) / 256, 256, 0, stream>>>(W, WtG);

    int nbE4 = (E / 4 + 255) / 256 + 1;   // 4 edges per thread (+1 covers tail)
    hist_kernel<<<nbE4, 256, 0, stream>>>(i1, i2, deg, E);
    scan_partials<<<NBS, 256, 0, stream>>>(deg, chunk, N);
    scan_offsets<<<1, 1024, 0, stream>>>(chunk, NBS);
    scan_final<<<NBS, 256, 0, stream>>>(deg, chunk, row_ptr, pos, N);
    fill_kernel<<<nbE4, 256, 0, stream>>>(i1, i2, pos, adjA, a1, a2, E);

    gather_transform<<<(N + NPB - 1) / NPB, 256, 0, stream>>>(
        e0, adjA, row_ptr, batch, WtG, b, graph_acc, N);

    finalize<<<(NGRAPH * H + 255) / 256, 256, 0, stream>>>(graph_acc, batch, out, N);
}